// Round 5
// baseline (267.045 us; speedup 1.0000x reference)
//
#include <hip/hip_runtime.h>
#include <hip/hip_bf16.h>

// CrossLocal: B=4, C=64, CI=32, cross 64x64 (Nc=4096), main 128x128.
// R5: LDS-free attention inner loop. Permuted-K S^T MFMA makes the packed
// exp results directly the A-fragment of the PV MFMA (no P transpose).
// 1024 blocks (16q x 4-way key split), SGPR pointer-advance addressing,
// BN stats fused into attn epilogue (atomics; stats zeroed via memset).
// ws: Qb[bf16 4*4096*32] Kb[same] Vt[bf16 4*32*4096] out2[f32 4*64*4096] stats[128]

typedef __attribute__((ext_vector_type(8))) short bf16x8;
typedef __attribute__((ext_vector_type(4))) float f32x4;

#define LOG2E 1.4426950408889634f

static __device__ __forceinline__ unsigned short f2bf_bits(float x) {
    __hip_bfloat16 h = __float2bfloat16(x);
    return *(unsigned short*)&h;
}
static __device__ __forceinline__ unsigned int pk2bf(float a, float b) {
    __hip_bfloat162 h = __float22bfloat162_rn(make_float2(a, b));
    return *(unsigned int*)&h;
}

// ---------------- Kernel 1: Q,K,V prep (bf16 out) ----------------
__global__ __launch_bounds__(256) void qkv_kernel(
    const float* __restrict__ cross, const float* __restrict__ mainf,
    const float* __restrict__ g_w,  const float* __restrict__ g_b,
    const float* __restrict__ th_w, const float* __restrict__ th_b,
    const float* __restrict__ ph_w, const float* __restrict__ ph_b,
    __hip_bfloat16* __restrict__ Qb, __hip_bfloat16* __restrict__ Kb,
    __hip_bfloat16* __restrict__ Vt)
{
    int gid  = blockIdx.x * 256 + threadIdx.x;   // 0..49151
    int kind = gid >> 14;                        // uniform per block
    int pix  = gid & 16383;
    int b = pix >> 12, n = pix & 4095;

    const float* w  = (kind == 0) ? g_w : (kind == 1) ? th_w : ph_w;
    const float* bs = (kind == 0) ? g_b : (kind == 1) ? th_b : ph_b;

    float acc[32];
#pragma unroll
    for (int ci = 0; ci < 32; ++ci) acc[ci] = bs[ci];

    if (kind < 2) {
        const float* cp = cross + (size_t)(b * 64) * 4096 + n;
        for (int c = 0; c < 64; ++c) {
            float xc = cp[(size_t)c * 4096];
#pragma unroll
            for (int ci = 0; ci < 32; ++ci)
                acc[ci] = fmaf(w[(ci << 6) + c], xc, acc[ci]);
        }
        if (kind == 0) {
#pragma unroll
            for (int ci = 0; ci < 32; ++ci) acc[ci] *= LOG2E;
        }
        unsigned int u[16];
#pragma unroll
        for (int i = 0; i < 16; ++i)
            u[i] = (unsigned int)f2bf_bits(acc[2 * i]) |
                   ((unsigned int)f2bf_bits(acc[2 * i + 1]) << 16);
        __hip_bfloat16* dst = ((kind == 0) ? Qb : Kb) + (size_t)pix * 32;
        uint4* d4 = (uint4*)dst;
#pragma unroll
        for (int r = 0; r < 4; ++r)
            d4[r] = make_uint4(u[4*r], u[4*r+1], u[4*r+2], u[4*r+3]);
    } else {
        int i = n >> 6, j = n & 63;
        const float* mp = mainf + (size_t)(b * 64) * 16384 + i * 256 + j * 2;
        for (int c = 0; c < 64; ++c) {
            const float* m = mp + (size_t)c * 16384;
            float xm = 0.25f * (m[0] + m[1] + m[128] + m[129]);
#pragma unroll
            for (int ci = 0; ci < 32; ++ci)
                acc[ci] = fmaf(w[(ci << 6) + c], xm, acc[ci]);
        }
#pragma unroll
        for (int ci = 0; ci < 32; ++ci)
            Vt[((size_t)((b << 5) | ci) << 12) + n] = __float2bfloat16(acc[ci]);
    }
}

// ---------------- Kernel 2: LDS-free MFMA flash attention + W conv + stats ----------------
// grid (256 qtiles of 16, 4 batch) x 256 thr. Wave w owns keys [w*1024,+1024),
// 32 chunks of 32 keys. K rows loaded permuted (perm(m)=8*(m>>2)+(m&3)) so the
// S^T C-layout exps pack directly into the PV A-fragment. No LDS in the loop.
__global__ __launch_bounds__(256) void attn_mfma(
    const __hip_bfloat16* __restrict__ Qb, const __hip_bfloat16* __restrict__ Kb,
    const __hip_bfloat16* __restrict__ Vt, const float* __restrict__ w_w,
    const float* __restrict__ w_b, float* __restrict__ out2,
    float* __restrict__ stats)
{
    __shared__ __align__(16) float redbuf[3][64][12];
    __shared__ __align__(16) float obuf[16][36];
    const int tid = threadIdx.x, lane = tid & 63, w = tid >> 6;
    const int lo = lane & 15, c = lane >> 4;
    const int b = blockIdx.y, qbase = blockIdx.x << 4;

    // Q fragment: Q[qbase+lo][8c..8c+7] (B-operand of S^T MFMA)
    const bf16x8 aq = *(const bf16x8*)(Qb + (((size_t)(b << 12) + qbase + lo) << 5) + (c << 3));

    const int perm   = ((lo >> 2) << 3) | (lo & 3);   // key-row permutation
    const int klane  = (perm << 5) + (c << 3);        // elements
    const int vlane0 = (lo << 12) + (c << 3);
    const int vlane1 = ((16 + lo) << 12) + (c << 3);

    const __hip_bfloat16* Kp = Kb + (((size_t)(b << 12)) << 5) + ((size_t)(w << 10) << 5);
    const __hip_bfloat16* Vp = Vt + (((size_t)(b << 5)) << 12) + (w << 10);

    f32x4 acc0 = {0.f,0.f,0.f,0.f}, acc1 = {0.f,0.f,0.f,0.f};
    float den = 0.f;
    const f32x4 z = {0.f,0.f,0.f,0.f};

#define LD(P, off) (*(const bf16x8*)((P) + (off)))
    bf16x8 ka0 = LD(Kp, klane), kb0 = LD(Kp, klane + 128);
    bf16x8 va0 = LD(Vp, vlane0), vb0 = LD(Vp, vlane1);
    Kp += 1024; Vp += 32;
    bf16x8 ka1 = LD(Kp, klane), kb1 = LD(Kp, klane + 128);
    bf16x8 va1 = LD(Vp, vlane0), vb1 = LD(Vp, vlane1);
    Kp += 1024; Vp += 32;

#define CHUNK(KA, KB, VA, VB)                                                   \
    {                                                                           \
        f32x4 s0 = __builtin_amdgcn_mfma_f32_16x16x32_bf16(KA, aq, z, 0, 0, 0); \
        f32x4 s1 = __builtin_amdgcn_mfma_f32_16x16x32_bf16(KB, aq, z, 0, 0, 0); \
        float p0 = __builtin_amdgcn_exp2f(s0[0]), p1 = __builtin_amdgcn_exp2f(s0[1]); \
        float p2 = __builtin_amdgcn_exp2f(s0[2]), p3 = __builtin_amdgcn_exp2f(s0[3]); \
        float q0 = __builtin_amdgcn_exp2f(s1[0]), q1 = __builtin_amdgcn_exp2f(s1[1]); \
        float q2 = __builtin_amdgcn_exp2f(s1[2]), q3 = __builtin_amdgcn_exp2f(s1[3]); \
        den += ((p0 + p1) + (p2 + p3)) + ((q0 + q1) + (q2 + q3));               \
        uint4 t = make_uint4(pk2bf(p0, p1), pk2bf(p2, p3),                      \
                             pk2bf(q0, q1), pk2bf(q2, q3));                     \
        bf16x8 ap = *(bf16x8*)&t;                                               \
        acc0 = __builtin_amdgcn_mfma_f32_16x16x32_bf16(ap, VA, acc0, 0, 0, 0);  \
        acc1 = __builtin_amdgcn_mfma_f32_16x16x32_bf16(ap, VB, acc1, 0, 0, 0);  \
    }

    for (int ch = 0; ch < 32; ch += 2) {
        CHUNK(ka0, kb0, va0, vb0);
        ka0 = LD(Kp, klane); kb0 = LD(Kp, klane + 128);     // chunk ch+2 (over-reads
        va0 = LD(Vp, vlane0); vb0 = LD(Vp, vlane1);         //  harmless at tail)
        Kp += 1024; Vp += 32;
        CHUNK(ka1, kb1, va1, vb1);
        ka1 = LD(Kp, klane); kb1 = LD(Kp, klane + 128);
        va1 = LD(Vp, vlane0); vb1 = LD(Vp, vlane1);
        Kp += 1024; Vp += 32;
    }
#undef CHUNK
#undef LD

    // den per lane covers its 8 keys for q=lo; reduce over c-groups
    den += __shfl_xor(den, 16);
    den += __shfl_xor(den, 32);

    // cross-wave combine: waves 1..3 dump, wave 0 adds
    if (w) {
        f32x4* rb = (f32x4*)&redbuf[w - 1][lane][0];
        rb[0] = acc0; rb[1] = acc1;
        f32x4 dv = {den, 0.f, 0.f, 0.f};
        rb[2] = dv;
    }
    __syncthreads();
    if (w == 0) {
#pragma unroll
        for (int ww = 0; ww < 3; ++ww) {
            const f32x4* rb = (const f32x4*)&redbuf[ww][lane][0];
            f32x4 a0 = rb[0], a1 = rb[1], dv = rb[2];
            acc0 += a0; acc1 += a1;
            den += dv[0];
        }
        // acc0[r] = O[q=4c+r][ci=lo], acc1[r] = O[q][ci=16+lo]; den is for q=lo
#pragma unroll
        for (int r = 0; r < 4; ++r) {
            float inv = 1.0f / __shfl(den, (c << 2) | r);
            obuf[(c << 2) | r][lo]      = acc0[r] * inv;
            obuf[(c << 2) | r][16 + lo] = acc1[r] * inv;
        }
    }
    __syncthreads();

    // ---- fused W 1x1 conv over the 16-query tile + BN partial stats ----
    const int q = tid & 15, cog = tid >> 4;   // 4 co per thread: co = kk*16+cog
    float ov[32];
    const float4* orow = (const float4*)&obuf[q][0];
#pragma unroll
    for (int k4 = 0; k4 < 8; ++k4) {
        float4 t = orow[k4];
        ov[4*k4] = t.x; ov[4*k4+1] = t.y; ov[4*k4+2] = t.z; ov[4*k4+3] = t.w;
    }
    float* dstbase = out2 + (((size_t)(b << 6)) << 12) + qbase + q;
    float vs[4], vs2[4];
#pragma unroll
    for (int kk = 0; kk < 4; ++kk) {
        int co = (kk << 4) | cog;
        const float4* wr = (const float4*)&w_w[co << 5];
        float acc = w_b[co];
#pragma unroll
        for (int k4 = 0; k4 < 8; ++k4) {
            float4 t = wr[k4];
            acc = fmaf(t.x, ov[4*k4],   acc);
            acc = fmaf(t.y, ov[4*k4+1], acc);
            acc = fmaf(t.z, ov[4*k4+2], acc);
            acc = fmaf(t.w, ov[4*k4+3], acc);
        }
        dstbase[(size_t)co << 12] = acc;
        vs[kk] = acc; vs2[kk] = acc * acc;
    }
    // reduce over q (= lane bits 0..3) via shuffles, then 1 atomic per co
#pragma unroll
    for (int off = 1; off < 16; off <<= 1) {
#pragma unroll
        for (int kk = 0; kk < 4; ++kk) {
            vs[kk]  += __shfl_xor(vs[kk],  off);
            vs2[kk] += __shfl_xor(vs2[kk], off);
        }
    }
    if ((lane & 15) == 0) {
#pragma unroll
        for (int kk = 0; kk < 4; ++kk) {
            int co = (kk << 4) | cog;
            atomicAdd(&stats[co],      vs[kk]);
            atomicAdd(&stats[64 + co], vs2[kk]);
        }
    }
}

// ---------------- Kernel 3: BN + bilinear 64->128 + residual ----------------
__global__ __launch_bounds__(256) void up_kernel(
    const float* __restrict__ out2, const float* __restrict__ stats,
    const float* __restrict__ gamma, const float* __restrict__ beta,
    const float* __restrict__ mainf, float* __restrict__ out)
{
    int idx = blockIdx.x * 256 + threadIdx.x;   // < 4*64*128*128
    int j  = idx & 127;
    int i  = (idx >> 7) & 127;
    int co = (idx >> 14) & 63;            // uniform within a block
    int b  = idx >> 20;

    float mean = stats[co] * (1.0f / 16384.0f);
    float var  = stats[64 + co] * (1.0f / 16384.0f) - mean * mean;
    float inv  = rsqrtf(var + 1e-5f);
    float scale = gamma[co] * inv;
    float shift = beta[co] - mean * scale;

    int ih = i >> 1, il = j >> 1;
    int k0, k1; float wi;
    if (i & 1)       { k0 = ih;     k1 = (ih < 63) ? ih + 1 : 63; wi = 0.25f; }
    else if (ih == 0){ k0 = 0;      k1 = 0;                       wi = 0.0f;  }
    else             { k0 = ih - 1; k1 = ih;                      wi = 0.75f; }
    int l0, l1; float wj;
    if (j & 1)       { l0 = il;     l1 = (il < 63) ? il + 1 : 63; wj = 0.25f; }
    else if (il == 0){ l0 = 0;      l1 = 0;                       wj = 0.0f;  }
    else             { l0 = il - 1; l1 = il;                      wj = 0.75f; }

    const float* p = out2 + ((size_t)((b << 6) | co) << 12);
    float v00 = p[(k0 << 6) | l0], v01 = p[(k0 << 6) | l1];
    float v10 = p[(k1 << 6) | l0], v11 = p[(k1 << 6) | l1];
    float top = v00 + wj * (v01 - v00);
    float bot = v10 + wj * (v11 - v10);
    float v = top + wi * (bot - top);
    out[idx] = fmaf(v, scale, shift) + mainf[idx];
}

extern "C" void kernel_launch(void* const* d_in, const int* in_sizes, int n_in,
                              void* d_out, int out_size, void* d_ws, size_t ws_size,
                              hipStream_t stream)
{
    const float* mainf = (const float*)d_in[0];
    const float* cross = (const float*)d_in[1];
    const float* g_w   = (const float*)d_in[2];
    const float* g_b   = (const float*)d_in[3];
    const float* th_w  = (const float*)d_in[4];
    const float* th_b  = (const float*)d_in[5];
    const float* ph_w  = (const float*)d_in[6];
    const float* ph_b  = (const float*)d_in[7];
    const float* w_w   = (const float*)d_in[8];
    const float* w_b   = (const float*)d_in[9];
    const float* gamma = (const float*)d_in[10];
    const float* beta  = (const float*)d_in[11];
    float* out = (float*)d_out;

    __hip_bfloat16* Qb = (__hip_bfloat16*)d_ws;     // 4*4096*32
    __hip_bfloat16* Kb = Qb + 524288;
    __hip_bfloat16* Vt = Kb + 524288;               // [b][ci][4096]
    float* out2  = (float*)(Vt + 524288);           // 4*64*4096
    float* stats = out2 + 1048576;                  // 128

    hipMemsetAsync(stats, 0, 128 * sizeof(float), stream);
    qkv_kernel<<<192, 256, 0, stream>>>(cross, mainf, g_w, g_b, th_w, th_b,
                                        ph_w, ph_b, Qb, Kb, Vt);
    attn_mfma<<<dim3(256, 4), 256, 0, stream>>>(Qb, Kb, Vt, w_w, w_b, out2, stats);
    up_kernel<<<16384, 256, 0, stream>>>(out2, stats, gamma, beta, mainf, out);
}

// Round 6
// 244.739 us; speedup vs baseline: 1.0911x; 1.0911x over previous
//
#include <hip/hip_runtime.h>
#include <hip/hip_bf16.h>

// CrossLocal: B=4, C=64, CI=32, cross 64x64 (Nc=4096), main 128x128.
// R6: R4's measured-best inner loop (S^T MFMA + LDS P-roundtrip with one-iter
// read-ahead), fixed query coverage: 32q blocks x 8 waves = 2 qg x 4-way key
// split. qkv parallelized 4x (8 ci/thread). BN stats fused into attn epilogue.
// ws: Qb[bf16 4*4096*32] Kb[same] Vt[bf16 4*32*4096] out2[f32 4*64*4096] stats[128]

typedef __attribute__((ext_vector_type(8))) short bf16x8;
typedef __attribute__((ext_vector_type(4))) float f32x4;

#define LOG2E 1.4426950408889634f

static __device__ __forceinline__ unsigned short f2bf_bits(float x) {
    __hip_bfloat16 h = __float2bfloat16(x);
    return *(unsigned short*)&h;
}
static __device__ __forceinline__ unsigned int pk2bf(float a, float b) {
    __hip_bfloat162 h = __float22bfloat162_rn(make_float2(a, b));
    return *(unsigned int*)&h;
}

// ---------------- Kernel 1: Q,K,V prep (bf16 out), 8 ci per thread ----------------
// gid: kind (gid>>16), cq ((gid>>14)&3), pix (gid&16383). 768 blocks.
__global__ __launch_bounds__(256) void qkv_kernel(
    const float* __restrict__ cross, const float* __restrict__ mainf,
    const float* __restrict__ g_w,  const float* __restrict__ g_b,
    const float* __restrict__ th_w, const float* __restrict__ th_b,
    const float* __restrict__ ph_w, const float* __restrict__ ph_b,
    __hip_bfloat16* __restrict__ Qb, __hip_bfloat16* __restrict__ Kb,
    __hip_bfloat16* __restrict__ Vt)
{
    int gid  = blockIdx.x * 256 + threadIdx.x;
    int kind = gid >> 16;                 // uniform per block
    int cq   = (gid >> 14) & 3;           // uniform per block
    int pix  = gid & 16383;
    int b = pix >> 12, n = pix & 4095;
    const int ci0 = cq << 3;

    const float* w  = (kind == 0) ? g_w : (kind == 1) ? th_w : ph_w;
    const float* bs = (kind == 0) ? g_b : (kind == 1) ? th_b : ph_b;

    float acc[8];
#pragma unroll
    for (int j = 0; j < 8; ++j) acc[j] = bs[ci0 + j];

    if (kind < 2) {
        const float* cp = cross + (size_t)(b * 64) * 4096 + n;
#pragma unroll 4
        for (int c = 0; c < 64; ++c) {
            float xc = cp[(size_t)c * 4096];
#pragma unroll
            for (int j = 0; j < 8; ++j)
                acc[j] = fmaf(w[((ci0 + j) << 6) + c], xc, acc[j]);
        }
        if (kind == 0) {
#pragma unroll
            for (int j = 0; j < 8; ++j) acc[j] *= LOG2E;
        }
        unsigned int u[4];
#pragma unroll
        for (int j = 0; j < 4; ++j)
            u[j] = (unsigned int)f2bf_bits(acc[2 * j]) |
                   ((unsigned int)f2bf_bits(acc[2 * j + 1]) << 16);
        __hip_bfloat16* dst = ((kind == 0) ? Qb : Kb) + (size_t)pix * 32 + ci0;
        *(uint4*)dst = make_uint4(u[0], u[1], u[2], u[3]);
    } else {
        int i = n >> 6, j2 = n & 63;
        const float* mp = mainf + (size_t)(b * 64) * 16384 + i * 256 + j2 * 2;
#pragma unroll 4
        for (int c = 0; c < 64; ++c) {
            const float2* m2 = (const float2*)(mp + (size_t)c * 16384);
            float2 t0 = m2[0], t1 = m2[64];
            float xm = 0.25f * ((t0.x + t0.y) + (t1.x + t1.y));
#pragma unroll
            for (int j = 0; j < 8; ++j)
                acc[j] = fmaf(w[((ci0 + j) << 6) + c], xm, acc[j]);
        }
#pragma unroll
        for (int j = 0; j < 8; ++j)
            Vt[((size_t)((b << 5) | (ci0 + j)) << 12) + n] = __float2bfloat16(acc[j]);
    }
}

// ---------------- Kernel 2: S^T-form MFMA flash attention + W conv + stats ----------------
// grid (128 qtiles of 32, 4 batch) x 512 thr (8 waves). Wave w: qg=w&1 (16 q),
// kh=w>>1 (1024 keys, 32 chunks of 32). R4's loop: S^T = mfma(K,Q) -> packed
// exps -> 2x ds_write_b64 -> ds_read_b128 (A-frag of P) issued one iteration
// ahead of its PV use.
__global__ __launch_bounds__(512) void attn_mfma(
    const __hip_bfloat16* __restrict__ Qb, const __hip_bfloat16* __restrict__ Kb,
    const __hip_bfloat16* __restrict__ Vt, const float* __restrict__ w_w,
    const float* __restrict__ w_b, float* __restrict__ out2,
    float* __restrict__ stats)
{
    __shared__ __align__(16) __hip_bfloat16 pbuf[8][2][16][40];
    __shared__ __align__(16) float redbuf[2][3][64][12];
    __shared__ __align__(16) float obuf[32][36];
    const int tid = threadIdx.x, lane = tid & 63, w = tid >> 6;
    const int lo = lane & 15, c = lane >> 4;
    const int qg = w & 1, kh = w >> 1;
    const int b = blockIdx.y;
    const int qbase = (blockIdx.x << 5) + (qg << 4);

    // Q fragment (B-operand of S^T MFMA)
    const bf16x8 aq = *(const bf16x8*)(Qb + (((size_t)(b << 12) + qbase + lo) << 5) + (c << 3));
    const __hip_bfloat16* Kbb = Kb + ((size_t)(b << 12) << 5);
    const __hip_bfloat16* Vbb = Vt + ((size_t)(b << 5) << 12);

    f32x4 acc0 = {0.f,0.f,0.f,0.f}, acc1 = {0.f,0.f,0.f,0.f};
    float den = 0.f;
    const f32x4 z = {0.f,0.f,0.f,0.f};
    const int kq = kh << 10;
#define LDK(k)      (*(const bf16x8*)(Kbb + ((size_t)((k) + lo) << 5) + (c << 3)))
#define LDV(k, cio) (*(const bf16x8*)(Vbb + ((size_t)(lo + (cio)) << 12) + (k) + (c << 3)))

    bf16x8 k0c = LDK(kq),      k1c = LDK(kq + 16);
    bf16x8 vB0 = LDV(kq, 0),   vB1 = LDV(kq, 16);
    bf16x8 k0n = LDK(kq + 32), k1n = LDK(kq + 48);
    bf16x8 vN0 = LDV(kq + 32, 0), vN1 = LDV(kq + 32, 16);
    bf16x8 ap;

    // ---- chunk 0: S phase + read-ahead ----
    {
        f32x4 s0 = __builtin_amdgcn_mfma_f32_16x16x32_bf16(k0c, aq, z, 0, 0, 0);
        f32x4 s1 = __builtin_amdgcn_mfma_f32_16x16x32_bf16(k1c, aq, z, 0, 0, 0);
        float p0 = __builtin_amdgcn_exp2f(s0[0]), p1 = __builtin_amdgcn_exp2f(s0[1]);
        float p2 = __builtin_amdgcn_exp2f(s0[2]), p3 = __builtin_amdgcn_exp2f(s0[3]);
        float q0 = __builtin_amdgcn_exp2f(s1[0]), q1 = __builtin_amdgcn_exp2f(s1[1]);
        float q2 = __builtin_amdgcn_exp2f(s1[2]), q3 = __builtin_amdgcn_exp2f(s1[3]);
        den += ((p0 + p1) + (p2 + p3)) + ((q0 + q1) + (q2 + q3));
        *(uint2*)&pbuf[w][0][lo][c << 2]        = make_uint2(pk2bf(p0, p1), pk2bf(p2, p3));
        *(uint2*)&pbuf[w][0][lo][16 + (c << 2)] = make_uint2(pk2bf(q0, q1), pk2bf(q2, q3));
        ap = *(const bf16x8*)&pbuf[w][0][lo][c << 3];
    }

#pragma unroll 2
    for (int ch = 1; ch < 32; ++ch) {
        const int kn = kq + ((ch + 1) & 31) * 32;
        bf16x8 vA0 = vB0, vA1 = vB1;
        vB0 = vN0; vB1 = vN1;
        k0c = k0n; k1c = k1n;
        k0n = LDK(kn); k1n = LDK(kn + 16);
        vN0 = LDV(kn, 0); vN1 = LDV(kn, 16);

        f32x4 s0 = __builtin_amdgcn_mfma_f32_16x16x32_bf16(k0c, aq, z, 0, 0, 0);
        f32x4 s1 = __builtin_amdgcn_mfma_f32_16x16x32_bf16(k1c, aq, z, 0, 0, 0);
        float p0 = __builtin_amdgcn_exp2f(s0[0]), p1 = __builtin_amdgcn_exp2f(s0[1]);
        float p2 = __builtin_amdgcn_exp2f(s0[2]), p3 = __builtin_amdgcn_exp2f(s0[3]);
        float q0 = __builtin_amdgcn_exp2f(s1[0]), q1 = __builtin_amdgcn_exp2f(s1[1]);
        float q2 = __builtin_amdgcn_exp2f(s1[2]), q3 = __builtin_amdgcn_exp2f(s1[3]);
        den += ((p0 + p1) + (p2 + p3)) + ((q0 + q1) + (q2 + q3));
        *(uint2*)&pbuf[w][ch & 1][lo][c << 2]        = make_uint2(pk2bf(p0, p1), pk2bf(p2, p3));
        *(uint2*)&pbuf[w][ch & 1][lo][16 + (c << 2)] = make_uint2(pk2bf(q0, q1), pk2bf(q2, q3));

        acc0 = __builtin_amdgcn_mfma_f32_16x16x32_bf16(ap, vA0, acc0, 0, 0, 0);
        acc1 = __builtin_amdgcn_mfma_f32_16x16x32_bf16(ap, vA1, acc1, 0, 0, 0);

        ap = *(const bf16x8*)&pbuf[w][ch & 1][lo][c << 3];
    }
    acc0 = __builtin_amdgcn_mfma_f32_16x16x32_bf16(ap, vB0, acc0, 0, 0, 0);
    acc1 = __builtin_amdgcn_mfma_f32_16x16x32_bf16(ap, vB1, acc1, 0, 0, 0);
#undef LDK
#undef LDV

    // den: reduce over c-groups (lane bits 4,5)
    den += __shfl_xor(den, 16);
    den += __shfl_xor(den, 32);

    // cross-wave combine over 4 key-quarters: kh>0 dump, kh==0 adds
    if (kh) {
        f32x4* rb = (f32x4*)&redbuf[qg][kh - 1][lane][0];
        rb[0] = acc0; rb[1] = acc1;
        f32x4 dv = {den, 0.f, 0.f, 0.f};
        rb[2] = dv;
    }
    __syncthreads();
    if (kh == 0) {
#pragma unroll
        for (int p = 0; p < 3; ++p) {
            const f32x4* rb = (const f32x4*)&redbuf[qg][p][lane][0];
            f32x4 a0 = rb[0], a1 = rb[1], dv = rb[2];
            acc0 += a0; acc1 += a1;
            den += dv[0];
        }
        // acc0[r] = O[q=4c+r][ci=lo], acc1[r] = O[q][16+lo]; den is for q=lo
#pragma unroll
        for (int r = 0; r < 4; ++r) {
            float inv = 1.0f / __shfl(den, (c << 2) | r);
            obuf[(qg << 4) | (c << 2) | r][lo]      = acc0[r] * inv;
            obuf[(qg << 4) | (c << 2) | r][16 + lo] = acc1[r] * inv;
        }
    }
    __syncthreads();

    // ---- fused W 1x1 conv (32 q x 64 co) + BN partial stats ----
    const int q = tid & 31, cog = tid >> 5;   // cog 0..15; co = kk*16+cog
    float ov[32];
    const float4* orow = (const float4*)&obuf[q][0];
#pragma unroll
    for (int k4 = 0; k4 < 8; ++k4) {
        float4 t = orow[k4];
        ov[4*k4] = t.x; ov[4*k4+1] = t.y; ov[4*k4+2] = t.z; ov[4*k4+3] = t.w;
    }
    float* dstbase = out2 + ((size_t)b << 18) + (blockIdx.x << 5) + q;
    float vs[4], vs2[4];
#pragma unroll
    for (int kk = 0; kk < 4; ++kk) {
        int co = (kk << 4) | cog;
        const float4* wr = (const float4*)&w_w[co << 5];
        float acc = w_b[co];
#pragma unroll
        for (int k4 = 0; k4 < 8; ++k4) {
            float4 t = wr[k4];
            acc = fmaf(t.x, ov[4*k4],   acc);
            acc = fmaf(t.y, ov[4*k4+1], acc);
            acc = fmaf(t.z, ov[4*k4+2], acc);
            acc = fmaf(t.w, ov[4*k4+3], acc);
        }
        dstbase[(size_t)co << 12] = acc;
        vs[kk] = acc; vs2[kk] = acc * acc;
    }
    // reduce over the 32 q-lanes sharing cog (offsets stay within half-wave)
#pragma unroll
    for (int off = 1; off < 32; off <<= 1) {
#pragma unroll
        for (int kk = 0; kk < 4; ++kk) {
            vs[kk]  += __shfl_xor(vs[kk],  off);
            vs2[kk] += __shfl_xor(vs2[kk], off);
        }
    }
    if ((lane & 31) == 0) {
#pragma unroll
        for (int kk = 0; kk < 4; ++kk) {
            int co = (kk << 4) | cog;
            atomicAdd(&stats[co],      vs[kk]);
            atomicAdd(&stats[64 + co], vs2[kk]);
        }
    }
}

// ---------------- Kernel 3: BN + bilinear 64->128 + residual ----------------
__global__ __launch_bounds__(256) void up_kernel(
    const float* __restrict__ out2, const float* __restrict__ stats,
    const float* __restrict__ gamma, const float* __restrict__ beta,
    const float* __restrict__ mainf, float* __restrict__ out)
{
    int idx = blockIdx.x * 256 + threadIdx.x;   // < 4*64*128*128
    int j  = idx & 127;
    int i  = (idx >> 7) & 127;
    int co = (idx >> 14) & 63;            // uniform within a block
    int b  = idx >> 20;

    float mean = stats[co] * (1.0f / 16384.0f);
    float var  = stats[64 + co] * (1.0f / 16384.0f) - mean * mean;
    float inv  = rsqrtf(var + 1e-5f);
    float scale = gamma[co] * inv;
    float shift = beta[co] - mean * scale;

    int ih = i >> 1, il = j >> 1;
    int k0, k1; float wi;
    if (i & 1)       { k0 = ih;     k1 = (ih < 63) ? ih + 1 : 63; wi = 0.25f; }
    else if (ih == 0){ k0 = 0;      k1 = 0;                       wi = 0.0f;  }
    else             { k0 = ih - 1; k1 = ih;                      wi = 0.75f; }
    int l0, l1; float wj;
    if (j & 1)       { l0 = il;     l1 = (il < 63) ? il + 1 : 63; wj = 0.25f; }
    else if (il == 0){ l0 = 0;      l1 = 0;                       wj = 0.0f;  }
    else             { l0 = il - 1; l1 = il;                      wj = 0.75f; }

    const float* p = out2 + ((size_t)((b << 6) | co) << 12);
    float v00 = p[(k0 << 6) | l0], v01 = p[(k0 << 6) | l1];
    float v10 = p[(k1 << 6) | l0], v11 = p[(k1 << 6) | l1];
    float top = v00 + wj * (v01 - v00);
    float bot = v10 + wj * (v11 - v10);
    float v = top + wi * (bot - top);
    out[idx] = fmaf(v, scale, shift) + mainf[idx];
}

extern "C" void kernel_launch(void* const* d_in, const int* in_sizes, int n_in,
                              void* d_out, int out_size, void* d_ws, size_t ws_size,
                              hipStream_t stream)
{
    const float* mainf = (const float*)d_in[0];
    const float* cross = (const float*)d_in[1];
    const float* g_w   = (const float*)d_in[2];
    const float* g_b   = (const float*)d_in[3];
    const float* th_w  = (const float*)d_in[4];
    const float* th_b  = (const float*)d_in[5];
    const float* ph_w  = (const float*)d_in[6];
    const float* ph_b  = (const float*)d_in[7];
    const float* w_w   = (const float*)d_in[8];
    const float* w_b   = (const float*)d_in[9];
    const float* gamma = (const float*)d_in[10];
    const float* beta  = (const float*)d_in[11];
    float* out = (float*)d_out;

    __hip_bfloat16* Qb = (__hip_bfloat16*)d_ws;     // 4*4096*32
    __hip_bfloat16* Kb = Qb + 524288;
    __hip_bfloat16* Vt = Kb + 524288;               // [b][ci][4096]
    float* out2  = (float*)(Vt + 524288);           // 4*64*4096
    float* stats = out2 + 1048576;                  // 128

    hipMemsetAsync(stats, 0, 128 * sizeof(float), stream);
    qkv_kernel<<<768, 256, 0, stream>>>(cross, mainf, g_w, g_b, th_w, th_b,
                                        ph_w, ph_b, Qb, Kb, Vt);
    attn_mfma<<<dim3(128, 4), 512, 0, stream>>>(Qb, Kb, Vt, w_w, w_b, out2, stats);
    up_kernel<<<16384, 256, 0, stream>>>(out2, stats, gamma, beta, mainf, out);
}

// Round 7
// 170.511 us; speedup vs baseline: 1.5661x; 1.4353x over previous
//
#include <hip/hip_runtime.h>
#include <hip/hip_bf16.h>

// CrossLocal: B=4, C=64, CI=32, cross 64x64 (Nc=4096), main 128x128.
// R7: attn/stats/up restored VERBATIM from R4 (best measured: attn 54us,
// VGPR 60 schedule — do not touch). qkv v3: LDS-staged inputs (cross/pooled
// main read exactly once, coalesced float4), wave-uniform weight FMAs.
// up v2: float4 IO, 4 outputs/thread.
// ws: Qb[bf16 4*4096*32] Kb[same] Vt[bf16 4*32*4096] out2[f32 4*64*4096] stats1[512]

typedef __attribute__((ext_vector_type(8))) short bf16x8;
typedef __attribute__((ext_vector_type(4))) float f32x4;

#define LOG2E 1.4426950408889634f

static __device__ __forceinline__ unsigned short f2bf_bits(float x) {
    __hip_bfloat16 h = __float2bfloat16(x);
    return *(unsigned short*)&h;
}
static __device__ __forceinline__ unsigned int pk2bf(float a, float b) {
    __hip_bfloat162 h = __float22bfloat162_rn(make_float2(a, b));
    return *(unsigned int*)&h;
}

// ---------------- Kernel 1: Q,K,V prep v3 (LDS-staged) ----------------
// grid 192 = 3 kinds x 16 px-blocks/batch x 4 batches. Block: 256 pixels.
// Stage x[64][256] in LDS (cross slice, or 2x2-pooled main), then each thread
// computes all 32 ci for its pixel. Weights are wave-uniform -> scalar loads.
__global__ __launch_bounds__(256) void qkv_kernel(
    const float* __restrict__ cross, const float* __restrict__ mainf,
    const float* __restrict__ g_w,  const float* __restrict__ g_b,
    const float* __restrict__ th_w, const float* __restrict__ th_b,
    const float* __restrict__ ph_w, const float* __restrict__ ph_b,
    __hip_bfloat16* __restrict__ Qb, __hip_bfloat16* __restrict__ Kb,
    __hip_bfloat16* __restrict__ Vt)
{
    __shared__ float xs[64][256];          // 64 KB
    const int kind = blockIdx.x >> 6;      // 0=Q,1=K,2=V
    const int pblk = blockIdx.x & 63;
    const int b = pblk >> 4, n0 = (pblk & 15) << 8;
    const int t = threadIdx.x;

    const float* w  = (kind == 0) ? g_w : (kind == 1) ? th_w : ph_w;
    const float* bs = (kind == 0) ? g_b : (kind == 1) ? th_b : ph_b;

    if (kind < 2) {
        const float* src = cross + (((size_t)(b * 64)) << 12) + n0;
        const int jr = (t & 63) << 2, c0 = t >> 6;
#pragma unroll
        for (int it = 0; it < 16; ++it) {
            int c = (it << 2) | c0;
            *(float4*)&xs[c][jr] = *(const float4*)(src + ((size_t)c << 12) + jr);
        }
    } else {
        // pooled main: xs[c][px]; lanes cover j-consecutive -> coalesced float2
        const int n = n0 + t;
        const int i2 = (n >> 6) << 1, j2 = (n & 63) << 1;
        const float* src = mainf + (((size_t)(b * 64)) << 14) + i2 * 128 + j2;
#pragma unroll 4
        for (int c = 0; c < 64; ++c) {
            const float2 a = *(const float2*)(src + ((size_t)c << 14));
            const float2 d = *(const float2*)(src + ((size_t)c << 14) + 128);
            xs[c][t] = 0.25f * ((a.x + a.y) + (d.x + d.y));
        }
    }
    __syncthreads();

    float acc[32];
#pragma unroll
    for (int ci = 0; ci < 32; ++ci) acc[ci] = bs[ci];
#pragma unroll 4
    for (int c = 0; c < 64; ++c) {
        float x = xs[c][t];
#pragma unroll
        for (int ci = 0; ci < 32; ++ci)
            acc[ci] = fmaf(w[(ci << 6) + c], x, acc[ci]);
    }

    const int pix = (b << 12) + n0 + t;
    if (kind < 2) {
        if (kind == 0) {
#pragma unroll
            for (int ci = 0; ci < 32; ++ci) acc[ci] *= LOG2E;
        }
        unsigned int u[16];
#pragma unroll
        for (int i = 0; i < 16; ++i)
            u[i] = (unsigned int)f2bf_bits(acc[2 * i]) |
                   ((unsigned int)f2bf_bits(acc[2 * i + 1]) << 16);
        __hip_bfloat16* dst = ((kind == 0) ? Qb : Kb) + (size_t)pix * 32;
        uint4* d4 = (uint4*)dst;
#pragma unroll
        for (int r = 0; r < 4; ++r)
            d4[r] = make_uint4(u[4*r], u[4*r+1], u[4*r+2], u[4*r+3]);
    } else {
        const int n = n0 + t;
#pragma unroll
        for (int ci = 0; ci < 32; ++ci)
            Vt[((size_t)((b << 5) | ci) << 12) + n] = __float2bfloat16(acc[ci]);
    }
}

// ---------------- Kernel 2: S^T-form MFMA flash attention + W conv ----------------
// VERBATIM R4 (measured 54us, VGPR-60 schedule). grid (128 qtiles of 32, 4
// batch) x 256 thr. Wave w: q-group w>>1 (16 q), key-half w&1 (2048 keys).
__global__ __launch_bounds__(256) void attn_mfma(
    const __hip_bfloat16* __restrict__ Qb, const __hip_bfloat16* __restrict__ Kb,
    const __hip_bfloat16* __restrict__ Vt, const float* __restrict__ w_w,
    const float* __restrict__ w_b, float* __restrict__ out2)
{
    __shared__ __align__(16) __hip_bfloat16 pbuf[4][2][16][40];
    __shared__ __align__(16) float redbuf[2][64][12];
    __shared__ __align__(16) float obuf[32][36];
    const int tid = threadIdx.x, lane = tid & 63, w = tid >> 6;
    const int lo = lane & 15, c = lane >> 4;
    const int kh = w & 1, qg = w >> 1;
    const int b = blockIdx.y;
    const int qbase = (blockIdx.x << 5) + (qg << 4);

    const bf16x8 aq = *(const bf16x8*)(Qb + (((size_t)(b << 12) + qbase + lo) << 5) + (c << 3));
    const __hip_bfloat16* Kbb = Kb + ((size_t)(b << 12) << 5);
    const __hip_bfloat16* Vbb = Vt + ((size_t)(b << 5) << 12);

    f32x4 acc0 = {0.f,0.f,0.f,0.f}, acc1 = {0.f,0.f,0.f,0.f};
    float den = 0.f;
    const f32x4 z = {0.f,0.f,0.f,0.f};
    const int kq = kh << 11;
#define LDK(k)      (*(const bf16x8*)(Kbb + ((size_t)((k) + lo) << 5) + (c << 3)))
#define LDV(k, cio) (*(const bf16x8*)(Vbb + ((size_t)(lo + (cio)) << 12) + (k) + (c << 3)))

    bf16x8 k0c = LDK(kq),      k1c = LDK(kq + 16);
    bf16x8 vB0 = LDV(kq, 0),   vB1 = LDV(kq, 16);
    bf16x8 k0n = LDK(kq + 32), k1n = LDK(kq + 48);
    bf16x8 vN0 = LDV(kq + 32, 0), vN1 = LDV(kq + 32, 16);
    bf16x8 ap;

    {
        f32x4 s0 = __builtin_amdgcn_mfma_f32_16x16x32_bf16(k0c, aq, z, 0, 0, 0);
        f32x4 s1 = __builtin_amdgcn_mfma_f32_16x16x32_bf16(k1c, aq, z, 0, 0, 0);
        float p0 = __builtin_amdgcn_exp2f(s0[0]), p1 = __builtin_amdgcn_exp2f(s0[1]);
        float p2 = __builtin_amdgcn_exp2f(s0[2]), p3 = __builtin_amdgcn_exp2f(s0[3]);
        float q0 = __builtin_amdgcn_exp2f(s1[0]), q1 = __builtin_amdgcn_exp2f(s1[1]);
        float q2 = __builtin_amdgcn_exp2f(s1[2]), q3 = __builtin_amdgcn_exp2f(s1[3]);
        den += ((p0 + p1) + (p2 + p3)) + ((q0 + q1) + (q2 + q3));
        uint2 wv0 = make_uint2(pk2bf(p0, p1), pk2bf(p2, p3));
        uint2 wv1 = make_uint2(pk2bf(q0, q1), pk2bf(q2, q3));
        *(uint2*)&pbuf[w][0][lo][c << 2]        = wv0;
        *(uint2*)&pbuf[w][0][lo][16 + (c << 2)] = wv1;
        ap = *(const bf16x8*)&pbuf[w][0][lo][c << 3];
    }

#pragma unroll 2
    for (int ch = 1; ch < 64; ++ch) {
        const int kn = kq + ((ch + 1) & 63) * 32;
        bf16x8 vA0 = vB0, vA1 = vB1;
        vB0 = vN0; vB1 = vN1;
        k0c = k0n; k1c = k1n;
        k0n = LDK(kn); k1n = LDK(kn + 16);
        vN0 = LDV(kn, 0); vN1 = LDV(kn, 16);

        f32x4 s0 = __builtin_amdgcn_mfma_f32_16x16x32_bf16(k0c, aq, z, 0, 0, 0);
        f32x4 s1 = __builtin_amdgcn_mfma_f32_16x16x32_bf16(k1c, aq, z, 0, 0, 0);
        float p0 = __builtin_amdgcn_exp2f(s0[0]), p1 = __builtin_amdgcn_exp2f(s0[1]);
        float p2 = __builtin_amdgcn_exp2f(s0[2]), p3 = __builtin_amdgcn_exp2f(s0[3]);
        float q0 = __builtin_amdgcn_exp2f(s1[0]), q1 = __builtin_amdgcn_exp2f(s1[1]);
        float q2 = __builtin_amdgcn_exp2f(s1[2]), q3 = __builtin_amdgcn_exp2f(s1[3]);
        den += ((p0 + p1) + (p2 + p3)) + ((q0 + q1) + (q2 + q3));
        uint2 wv0 = make_uint2(pk2bf(p0, p1), pk2bf(p2, p3));
        uint2 wv1 = make_uint2(pk2bf(q0, q1), pk2bf(q2, q3));
        *(uint2*)&pbuf[w][ch & 1][lo][c << 2]        = wv0;
        *(uint2*)&pbuf[w][ch & 1][lo][16 + (c << 2)] = wv1;

        acc0 = __builtin_amdgcn_mfma_f32_16x16x32_bf16(ap, vA0, acc0, 0, 0, 0);
        acc1 = __builtin_amdgcn_mfma_f32_16x16x32_bf16(ap, vA1, acc1, 0, 0, 0);

        ap = *(const bf16x8*)&pbuf[w][ch & 1][lo][c << 3];
    }
    acc0 = __builtin_amdgcn_mfma_f32_16x16x32_bf16(ap, vB0, acc0, 0, 0, 0);
    acc1 = __builtin_amdgcn_mfma_f32_16x16x32_bf16(ap, vB1, acc1, 0, 0, 0);
#undef LDK
#undef LDV

    den += __shfl_xor(den, 16);
    den += __shfl_xor(den, 32);

    if (kh) {
        f32x4* rb = (f32x4*)&redbuf[qg][lane][0];
        rb[0] = acc0; rb[1] = acc1;
        f32x4 dv = {den, 0.f, 0.f, 0.f};
        rb[2] = dv;
    }
    __syncthreads();
    if (kh == 0) {
        const f32x4* rb = (const f32x4*)&redbuf[qg][lane][0];
        f32x4 a0 = rb[0], a1 = rb[1], dv = rb[2];
        acc0 += a0; acc1 += a1;
        den += dv[0];
#pragma unroll
        for (int r = 0; r < 4; ++r) {
            float inv = 1.0f / __shfl(den, (c << 2) | r);
            obuf[(qg << 4) | (c << 2) | r][lo]      = acc0[r] * inv;
            obuf[(qg << 4) | (c << 2) | r][16 + lo] = acc1[r] * inv;
        }
    }
    __syncthreads();

    const int q = tid & 31, cog = tid >> 5;   // 8 co per thread
    float ov[32];
    const float4* orow = (const float4*)&obuf[q][0];
#pragma unroll
    for (int k4 = 0; k4 < 8; ++k4) {
        float4 t = orow[k4];
        ov[4*k4] = t.x; ov[4*k4+1] = t.y; ov[4*k4+2] = t.z; ov[4*k4+3] = t.w;
    }
    float* dstbase = out2 + (((size_t)(b << 6)) << 12) + (blockIdx.x << 5) + q;
#pragma unroll
    for (int kk = 0; kk < 8; ++kk) {
        int co = (kk << 3) | cog;
        const float4* wr = (const float4*)&w_w[co << 5];
        float acc = w_b[co];
#pragma unroll
        for (int k4 = 0; k4 < 8; ++k4) {
            float4 t = wr[k4];
            acc = fmaf(t.x, ov[4*k4],   acc);
            acc = fmaf(t.y, ov[4*k4+1], acc);
            acc = fmaf(t.z, ov[4*k4+2], acc);
            acc = fmaf(t.w, ov[4*k4+3], acc);
        }
        dstbase[(size_t)co << 12] = acc;
    }
}

// ---------------- Kernel 3: BN partial statistics (per channel, per batch) ----------------
__global__ __launch_bounds__(256) void stats_kernel(
    const float* __restrict__ out2, float* __restrict__ stats1)
{
    int co = blockIdx.x >> 2, b = blockIdx.x & 3, t = threadIdx.x;
    const float* p = out2 + ((size_t)((b << 6) | co) << 12);
    float s = 0.f, s2 = 0.f;
#pragma unroll
    for (int ii = 0; ii < 16; ++ii) {
        float v = p[(ii << 8) | t];
        s += v; s2 = fmaf(v, v, s2);
    }
    __shared__ float rs[256], rs2[256];
    rs[t] = s; rs2[t] = s2;
    __syncthreads();
    for (int off = 128; off > 0; off >>= 1) {
        if (t < off) { rs[t] += rs[t + off]; rs2[t] += rs2[t + off]; }
        __syncthreads();
    }
    if (t == 0) {
        stats1[blockIdx.x * 2]     = rs[0];
        stats1[blockIdx.x * 2 + 1] = rs2[0];
    }
}

// ---------------- Kernel 4: BN + bilinear 64->128 + residual (float4) ----------------
__global__ __launch_bounds__(256) void up_kernel(
    const float* __restrict__ out2, const float* __restrict__ stats1,
    const float* __restrict__ gamma, const float* __restrict__ beta,
    const float* __restrict__ mainf, float* __restrict__ out)
{
    int gid = blockIdx.x * 256 + threadIdx.x;   // < 4*64*128*32
    int j4 = (gid & 31) << 2;
    int i  = (gid >> 5) & 127;
    int co = (gid >> 12) & 63;            // uniform within a block
    int b  = gid >> 18;

    float sm = 0.f, sq = 0.f;
#pragma unroll
    for (int bb = 0; bb < 4; ++bb) {
        sm += stats1[((co << 2) | bb) * 2];
        sq += stats1[((co << 2) | bb) * 2 + 1];
    }
    float mean = sm * (1.0f / 16384.0f);
    float var  = sq * (1.0f / 16384.0f) - mean * mean;
    float inv  = rsqrtf(var + 1e-5f);
    float scale = gamma[co] * inv;
    float shift = beta[co] - mean * scale;

    int ih = i >> 1;
    int k0, k1; float wi;
    if (i & 1)       { k0 = ih;     k1 = (ih < 63) ? ih + 1 : 63; wi = 0.25f; }
    else if (ih == 0){ k0 = 0;      k1 = 0;                       wi = 0.0f;  }
    else             { k0 = ih - 1; k1 = ih;                      wi = 0.75f; }

    const float* p0r = out2 + ((size_t)((b << 6) | co) << 12) + (k0 << 6);
    const float* p1r = out2 + ((size_t)((b << 6) | co) << 12) + (k1 << 6);

    float res[4];
#pragma unroll
    for (int jj = 0; jj < 4; ++jj) {
        int j = j4 | jj;
        int il = j >> 1;
        int l0, l1; float wj;
        if (j & 1)       { l0 = il;     l1 = (il < 63) ? il + 1 : 63; wj = 0.25f; }
        else if (il == 0){ l0 = 0;      l1 = 0;                       wj = 0.0f;  }
        else             { l0 = il - 1; l1 = il;                      wj = 0.75f; }
        float v00 = p0r[l0], v01 = p0r[l1];
        float v10 = p1r[l0], v11 = p1r[l1];
        float top = v00 + wj * (v01 - v00);
        float bot = v10 + wj * (v11 - v10);
        float v = top + wi * (bot - top);
        res[jj] = fmaf(v, scale, shift);
    }
    size_t idx = (((size_t)((b << 6) | co)) << 14) + (i << 7) + j4;
    float4 m4 = *(const float4*)(mainf + idx);
    *(float4*)(out + idx) = make_float4(res[0] + m4.x, res[1] + m4.y,
                                        res[2] + m4.z, res[3] + m4.w);
}

extern "C" void kernel_launch(void* const* d_in, const int* in_sizes, int n_in,
                              void* d_out, int out_size, void* d_ws, size_t ws_size,
                              hipStream_t stream)
{
    const float* mainf = (const float*)d_in[0];
    const float* cross = (const float*)d_in[1];
    const float* g_w   = (const float*)d_in[2];
    const float* g_b   = (const float*)d_in[3];
    const float* th_w  = (const float*)d_in[4];
    const float* th_b  = (const float*)d_in[5];
    const float* ph_w  = (const float*)d_in[6];
    const float* ph_b  = (const float*)d_in[7];
    const float* w_w   = (const float*)d_in[8];
    const float* w_b   = (const float*)d_in[9];
    const float* gamma = (const float*)d_in[10];
    const float* beta  = (const float*)d_in[11];
    float* out = (float*)d_out;

    __hip_bfloat16* Qb = (__hip_bfloat16*)d_ws;     // 4*4096*32
    __hip_bfloat16* Kb = Qb + 524288;
    __hip_bfloat16* Vt = Kb + 524288;               // [b][ci][4096]
    float* out2   = (float*)(Vt + 524288);          // 4*64*4096
    float* stats1 = out2 + 1048576;                 // 512

    qkv_kernel<<<192, 256, 0, stream>>>(cross, mainf, g_w, g_b, th_w, th_b,
                                        ph_w, ph_b, Qb, Kb, Vt);
    attn_mfma<<<dim3(128, 4), 256, 0, stream>>>(Qb, Kb, Vt, w_w, w_b, out2);
    stats_kernel<<<256, 256, 0, stream>>>(out2, stats1);
    up_kernel<<<4096, 256, 0, stream>>>(out2, stats1, gamma, beta, mainf, out);
}